// Round 4
// baseline (524.404 us; speedup 1.0000x reference)
//
#include <hip/hip_runtime.h>
#include <hip/hip_cooperative_groups.h>

namespace cg = cooperative_groups;

#define NB 8
#define NC 256
#define DF 16384
#define KCL 16
#define SPLITS 16
#define KC (DF / SPLITS)     // 1024
#define BK 32
#define ITERS (KC / BK)      // 32
#define NTILE 10

typedef _Float16 half8 __attribute__((ext_vector_type(8)));
typedef float floatx4 __attribute__((ext_vector_type(4)));

__device__ const int TItab[NTILE] = {0,0,0,0,1,1,1,2,2,3};
__device__ const int TJtab[NTILE] = {0,1,2,3,1,2,3,2,3,3};

// ---------------- reduction helper: argmax over 256 threads, first-occurrence ----
__device__ __forceinline__ int argmax256(float v, float* sv, int* si) {
  int t = threadIdx.x;
  sv[t] = v; si[t] = t;
  __syncthreads();
  #pragma unroll
  for (int s = 128; s >= 1; s >>= 1) {
    if (t < s) {
      float a = sv[t], b = sv[t + s];
      int ia = si[t], ib = si[t + s];
      if (b > a || (b == a && ib < ia)) { sv[t] = b; si[t] = ib; }
    }
    __syncthreads();
  }
  int r = si[0];
  __syncthreads();
  return r;
}

// ---------------- K1: pos FPS, fully in-LDS (no Dpos buffer) ---------------------
__global__ __launch_bounds__(256) void k_pre(const float* __restrict__ pe,
                                             float* __restrict__ centers0) {
  __shared__ float px[NC], py[NC], pz[NC], pn[NC];
  __shared__ float sv[NC]; __shared__ int si[NC];
  __shared__ int fpsIdx[KCL];
  int t = threadIdx.x;
  float x = pe[t * 3 + 0], y = pe[t * 3 + 1], z = pe[t * 3 + 2];
  px[t] = x; py[t] = y; pz[t] = z;
  float n = x * x + y * y + z * z;
  pn[t] = n;
  __syncthreads();
  float rs = 0.f;
  for (int j = 0; j < NC; ++j) {
    float dot = x * px[j] + y * py[j] + z * pz[j];
    float d2 = n + pn[j] - 2.f * dot;
    rs += sqrtf(fmaxf(d2, 0.f));
  }
  int start = argmax256(rs, sv, si);
  if (t == 0) fpsIdx[0] = start;
  // recompute D(far,t) from coords each iteration (identical formula, symmetric)
  float dot0 = x * px[start] + y * py[start] + z * pz[start];
  float mind = sqrtf(fmaxf(n + pn[start] - 2.f * dot0, 0.f));
  for (int it = 1; it < KCL; ++it) {
    int far = argmax256(mind, sv, si);
    if (t == 0) fpsIdx[it] = far;
    float dot = x * px[far] + y * py[far] + z * pz[far];
    mind = fminf(mind, sqrtf(fmaxf(n + pn[far] - 2.f * dot, 0.f)));
  }
  __syncthreads();
  if (t < KCL) {
    int p = fpsIdx[t];
    centers0[t * 3 + 0] = px[p];
    centers0[t * 3 + 1] = py[p];
    centers0[t * 3 + 2] = pz[p];
  }
}

// ---------------- K2: MFMA Gram, upper-tri 64x64 tiles, 3 chains, split-K=16 -----
__global__ __launch_bounds__(256, 5) void k_gemm_mfma(const float* __restrict__ ff,
                                                      float* __restrict__ Pp) {
  __shared__ _Float16 Ah[64][40];
  __shared__ _Float16 Al[64][40];
  __shared__ _Float16 Bh[64][40];
  __shared__ _Float16 Bl[64][40];

  const int tid = threadIdx.x;
  const int tp = blockIdx.x;
  const int ti = TItab[tp], tj = TJtab[tp];
  const bool diag = (ti == tj);
  const int b = blockIdx.y, sp = blockIdx.z;
  const int wave = tid >> 6, lane = tid & 63;
  const int lrow = lane & 15, q = lane >> 4;

  const int sr = tid >> 2;
  const int sc = (tid & 3) * 8;
  const float* gA = ff + ((size_t)(b * NC + ti * 64 + sr)) * DF + sp * KC + sc;
  const float* gB = ff + ((size_t)(b * NC + tj * 64 + sr)) * DF + sp * KC + sc;

  floatx4 a1[4], a2[4], a3[4];
  #pragma unroll
  for (int j = 0; j < 4; ++j) { a1[j] = (floatx4)0.f; a2[j] = (floatx4)0.f; a3[j] = (floatx4)0.f; }

  float4 ra0 = *(const float4*)(gA), ra1 = *(const float4*)(gA + 4);
  float4 rb0 = make_float4(0.f, 0.f, 0.f, 0.f), rb1 = rb0;
  if (!diag) { rb0 = *(const float4*)(gB); rb1 = *(const float4*)(gB + 4); }
  gA += BK; gB += BK;

  for (int it = 0; it < ITERS; ++it) {
    float fa[8] = {ra0.x, ra0.y, ra0.z, ra0.w, ra1.x, ra1.y, ra1.z, ra1.w};
    half8 ah, al;
    #pragma unroll
    for (int e = 0; e < 8; ++e) {
      _Float16 h = (_Float16)fa[e];
      ah[e] = h;
      al[e] = (_Float16)(fa[e] - (float)h);
    }
    half8 bh, bl;
    if (!diag) {
      float fb[8] = {rb0.x, rb0.y, rb0.z, rb0.w, rb1.x, rb1.y, rb1.z, rb1.w};
      #pragma unroll
      for (int e = 0; e < 8; ++e) {
        _Float16 h = (_Float16)fb[e];
        bh[e] = h;
        bl[e] = (_Float16)(fb[e] - (float)h);
      }
    }
    __syncthreads();
    *(half8*)&Ah[sr][sc] = ah;
    *(half8*)&Al[sr][sc] = al;
    if (!diag) {
      *(half8*)&Bh[sr][sc] = bh;
      *(half8*)&Bl[sr][sc] = bl;
    }
    __syncthreads();
    if (it + 1 < ITERS) {
      ra0 = *(const float4*)(gA); ra1 = *(const float4*)(gA + 4);
      if (!diag) { rb0 = *(const float4*)(gB); rb1 = *(const float4*)(gB + 4); }
      gA += BK; gB += BK;
    }
    const _Float16* bhp = diag ? &Ah[0][0] : &Bh[0][0];
    const _Float16* blp = diag ? &Al[0][0] : &Bl[0][0];
    half8 af = *(const half8*)&Ah[wave * 16 + lrow][q * 8];
    half8 lf = *(const half8*)&Al[wave * 16 + lrow][q * 8];
    #pragma unroll
    for (int j = 0; j < 4; ++j) {
      half8 bhf = *(const half8*)(bhp + (j * 16 + lrow) * 40 + q * 8);
      half8 blf = *(const half8*)(blp + (j * 16 + lrow) * 40 + q * 8);
      a1[j] = __builtin_amdgcn_mfma_f32_16x16x32_f16(af, bhf, a1[j], 0, 0, 0);
      a2[j] = __builtin_amdgcn_mfma_f32_16x16x32_f16(af, blf, a2[j], 0, 0, 0);
      a3[j] = __builtin_amdgcn_mfma_f32_16x16x32_f16(lf, bhf, a3[j], 0, 0, 0);
    }
  }

  float* Pb = Pp + (size_t)(sp * NB + b) * NC * NC;
  int grow = ti * 64 + wave * 16 + q * 4;
  #pragma unroll
  for (int j = 0; j < 4; ++j) {
    int gcol = tj * 64 + j * 16 + lrow;
    float4 v;
    v.x = a1[j][0] + a2[j][0] + a3[j][0];
    v.y = a1[j][1] + a2[j][1] + a3[j][1];
    v.z = a1[j][2] + a2[j][2] + a3[j][2];
    v.w = a1[j][3] + a2[j][3] + a3[j][3];
    Pb[(size_t)(grow + 0) * NC + gcol] = v.x;
    Pb[(size_t)(grow + 1) * NC + gcol] = v.y;
    Pb[(size_t)(grow + 2) * NC + gcol] = v.z;
    Pb[(size_t)(grow + 3) * NC + gcol] = v.w;
    if (!diag) *(float4*)&Pb[(size_t)gcol * NC + grow] = v;
  }
}

// ---------------- K3: cooperative — diag | formD | FPS | final -------------------
__global__ __launch_bounds__(256) void k_coop(const float* __restrict__ pe,
                                              const float* __restrict__ Pp,
                                              float* __restrict__ dg,
                                              float* __restrict__ Db,
                                              const float* __restrict__ centers0,
                                              float* __restrict__ ccoord,
                                              int* __restrict__ outp) {
  cg::grid_group grid = cg::this_grid();
  __shared__ float sv[NC]; __shared__ int si[NC];
  __shared__ int fpsIdx[KCL];
  const int t = threadIdx.x, g = blockIdx.x;

  // ---- phase 0: diag (blocks 0..7) ----
  if (g < NB) {
    float s = 0.f;
    #pragma unroll
    for (int sp = 0; sp < SPLITS; ++sp)
      s += Pp[((size_t)(sp * NB + g) * NC + t) * NC + t];
    dg[g * NC + t] = s;
  }
  __threadfence();
  grid.sync();

  // ---- phase 1: formD (all 256 blocks, 8 rows each) ----
  {
    int b = g >> 5, i0 = (g & 31) * 8;
    float dgj = dg[b * NC + t];
    for (int ii = 0; ii < 8; ++ii) {
      int i = i0 + ii;
      float acc = 0.f;
      #pragma unroll
      for (int sp = 0; sp < SPLITS; ++sp)
        acc += Pp[((size_t)(sp * NB + b) * NC + i) * NC + t];
      float d2 = dg[b * NC + i] + dgj - 2.f * acc;
      Db[((size_t)b * NC + i) * NC + t] = sqrtf(fmaxf(d2, 0.f));
    }
  }
  __threadfence();
  grid.sync();

  // ---- phase 2: FPS per batch (blocks 0..7) ----
  if (g < NB) {
    const float* D = Db + (size_t)g * NC * NC;
    float rs = 0.f;
    #pragma unroll 8
    for (int i = 0; i < NC; ++i) rs += D[i * NC + t];   // symmetric -> column sums
    int start = argmax256(rs, sv, si);
    if (t == 0) fpsIdx[0] = start;
    float mind = D[start * NC + t];
    for (int it = 1; it < KCL; ++it) {
      int far = argmax256(mind, sv, si);
      if (t == 0) fpsIdx[it] = far;
      mind = fminf(mind, D[far * NC + t]);
    }
    __syncthreads();
    if (t < KCL) {
      int p = fpsIdx[t];
      ccoord[(g * KCL + t) * 3 + 0] = pe[(g * NC + p) * 3 + 0];
      ccoord[(g * KCL + t) * 3 + 1] = pe[(g * NC + p) * 3 + 1];
      ccoord[(g * KCL + t) * 3 + 2] = pe[(g * NC + p) * 3 + 2];
    }
  }
  __threadfence();
  grid.sync();

  // ---- phase 3: block 0 — temp assign + means + matching + update + capacity ----
  if (g == 0) {
    __shared__ float cc[NB * KCL * 3];
    __shared__ float cn[NB * KCL];
    __shared__ float sums[KCL][3];
    __shared__ int cnts[KCL];
    __shared__ float avg[KCL][3];
    __shared__ float an[KCL];
    __shared__ float c0[KCL * 3];
    __shared__ float c1x[KCL], c1y[KCL], c1z[KCL], c1n[KCL];
    __shared__ int order[NC][KCL];
    for (int i = t; i < NB * KCL * 3; i += 256) cc[i] = ccoord[i];
    if (t < KCL * 3) c0[t] = centers0[t];
    if (t < KCL) { sums[t][0] = 0.f; sums[t][1] = 0.f; sums[t][2] = 0.f; cnts[t] = 0; }
    __syncthreads();
    if (t < NB * KCL) {
      float x = cc[t * 3], y = cc[t * 3 + 1], z = cc[t * 3 + 2];
      cn[t] = x * x + y * y + z * z;
    }
    __syncthreads();
    for (int b = 0; b < NB; ++b) {
      int p = b * NC + t;
      float x = pe[p * 3], y = pe[p * 3 + 1], z = pe[p * 3 + 2];
      float n = x * x + y * y + z * z;
      float best = 3.4e38f; int bi = 0;
      #pragma unroll
      for (int k = 0; k < KCL; ++k) {
        int c = b * KCL + k;
        float dot = x * cc[c * 3] + y * cc[c * 3 + 1] + z * cc[c * 3 + 2];
        float d2 = fmaxf(n + cn[c] - 2.f * dot, 0.f);
        if (d2 < best) { best = d2; bi = k; }
      }
      atomicAdd(&sums[bi][0], x);
      atomicAdd(&sums[bi][1], y);
      atomicAdd(&sums[bi][2], z);
      atomicAdd(&cnts[bi], 1);
    }
    __syncthreads();
    if (t < KCL) {
      float c = (float)cnts[t];
      float inv = 1.f / fmaxf(c, 1.f);
      float ax = (cnts[t] > 0) ? sums[t][0] * inv : 0.f;
      float ay = (cnts[t] > 0) ? sums[t][1] * inv : 0.f;
      float az = (cnts[t] > 0) ? sums[t][2] * inv : 0.f;
      avg[t][0] = ax; avg[t][1] = ay; avg[t][2] = az;
      an[t] = ax * ax + ay * ay + az * az;
    }
    __syncthreads();
    if (t < KCL) {
      float x = c0[t * 3], y = c0[t * 3 + 1], z = c0[t * 3 + 2];
      float n = x * x + y * y + z * z;
      float best = 3.4e38f; int bi = 0;
      #pragma unroll
      for (int j = 0; j < KCL; ++j) {
        float dot = x * avg[j][0] + y * avg[j][1] + z * avg[j][2];
        float d2 = fmaxf(n + an[j] - 2.f * dot, 0.f);
        if (d2 < best) { best = d2; bi = j; }
      }
      float nx = 0.8f * x + 0.2f * avg[bi][0];
      float ny = 0.8f * y + 0.2f * avg[bi][1];
      float nz = 0.8f * z + 0.2f * avg[bi][2];
      c1x[t] = nx; c1y[t] = ny; c1z[t] = nz;
      c1n[t] = nx * nx + ny * ny + nz * nz;
    }
    __syncthreads();
    {
      float x = pe[t * 3], y = pe[t * 3 + 1], z = pe[t * 3 + 2];
      float n = x * x + y * y + z * z;
      float v[KCL];
      #pragma unroll
      for (int k = 0; k < KCL; ++k) {
        float dot = x * c1x[k] + y * c1y[k] + z * c1z[k];
        v[k] = fmaxf(n + c1n[k] - 2.f * dot, 0.f);
      }
      bool used[KCL];
      #pragma unroll
      for (int k = 0; k < KCL; ++k) used[k] = false;
      for (int r = 0; r < KCL; ++r) {
        float best = 3.4e38f; int bi = 0;
        #pragma unroll
        for (int j = 0; j < KCL; ++j) {
          if (!used[j] && v[j] < best) { best = v[j]; bi = j; }
        }
        order[t][r] = bi;
        used[bi] = true;
      }
    }
    __syncthreads();
    if (t < 64) {
      int cnt = 0;
      int cur = (t < KCL) ? order[0][t] : 0;
      for (int i = 0; i < NC; ++i) {
        int nxt = (t < KCL && i + 1 < NC) ? order[i + 1][t] : 0;
        int ccur = __shfl(cnt, cur);
        bool avail = (t < KCL) && (ccur < 16);
        unsigned long long m = __ballot(avail);
        int chosen;
        if (m != 0ull) {
          int rank = __ffsll((unsigned long long)m) - 1;
          chosen = __shfl(cur, rank);
        } else {
          chosen = __shfl(cur, 0);
        }
        if (t == chosen) cnt++;
        if (t == 0) outp[i] = chosen;
        cur = nxt;
      }
    }
  }
}

extern "C" void kernel_launch(void* const* d_in, const int* in_sizes, int n_in,
                              void* d_out, int out_size, void* d_ws, size_t ws_size,
                              hipStream_t stream) {
  (void)in_sizes; (void)n_in; (void)out_size; (void)ws_size;
  const float* features = (const float*)d_in[0];
  const float* pe = (const float*)d_in[1];
  char* ws = (char*)d_ws;
  float* Pp       = (float*)(ws);                  // 16*8*256*256*4 = 32 MiB
  float* Db       = (float*)(ws + 33554432);       // 2 MiB
  float* dg       = (float*)(ws + 35651584);       // 8 KiB
  float* centers0 = (float*)(ws + 35659776);       // 192 B
  float* ccoord   = (float*)(ws + 35660288);       // 1.5 KiB
  int*   outp     = (int*)d_out;

  hipLaunchKernelGGL(k_pre, dim3(1), dim3(256), 0, stream, pe, centers0);
  hipLaunchKernelGGL(k_gemm_mfma, dim3(NTILE, NB, SPLITS), dim3(256), 0, stream, features, Pp);

  void* args[] = {(void*)&pe, (void*)&Pp, (void*)&dg, (void*)&Db,
                  (void*)&centers0, (void*)&ccoord, (void*)&outp};
  hipLaunchCooperativeKernel((void*)k_coop, dim3(256), dim3(256), args, 0, stream);
}

// Round 5
// 366.399 us; speedup vs baseline: 1.4312x; 1.4312x over previous
//
#include <hip/hip_runtime.h>

#define NB 8
#define NC 256
#define DF 16384
#define KCL 16
#define SPLITS 16
#define KC (DF / SPLITS)     // 1024
#define BK 32
#define ITERS (KC / BK)      // 32
#define NTILE 3              // 128x128 upper-tri pairs: (0,0),(0,1),(1,1)

typedef _Float16 half8 __attribute__((ext_vector_type(8)));
typedef float floatx4 __attribute__((ext_vector_type(4)));

__device__ const int TItab[NTILE] = {0,0,1};
__device__ const int TJtab[NTILE] = {0,1,1};

// ---------------- reduction helper: argmax over 256 threads, first-occurrence ----
__device__ __forceinline__ int argmax256(float v, float* sv, int* si) {
  int t = threadIdx.x;
  sv[t] = v; si[t] = t;
  __syncthreads();
  #pragma unroll
  for (int s = 128; s >= 1; s >>= 1) {
    if (t < s) {
      float a = sv[t], b = sv[t + s];
      int ia = si[t], ib = si[t + s];
      if (b > a || (b == a && ib < ia)) { sv[t] = b; si[t] = ib; }
    }
    __syncthreads();
  }
  int r = si[0];
  __syncthreads();
  return r;
}

// ---------------- K1: pos FPS in-LDS + zero rs ----------------------------------
__global__ __launch_bounds__(256) void k_pre(const float* __restrict__ pe,
                                             float* __restrict__ centers0,
                                             float* __restrict__ rs) {
  __shared__ float px[NC], py[NC], pz[NC], pn[NC];
  __shared__ float sv[NC]; __shared__ int si[NC];
  __shared__ int fpsIdx[KCL];
  int t = threadIdx.x;
  for (int i = t; i < NB * NC; i += 256) rs[i] = 0.f;   // zero-init (ws is poisoned)
  float x = pe[t * 3 + 0], y = pe[t * 3 + 1], z = pe[t * 3 + 2];
  px[t] = x; py[t] = y; pz[t] = z;
  float n = x * x + y * y + z * z;
  pn[t] = n;
  __syncthreads();
  float rsum = 0.f;
  for (int j = 0; j < NC; ++j) {
    float dot = x * px[j] + y * py[j] + z * pz[j];
    float d2 = n + pn[j] - 2.f * dot;
    rsum += sqrtf(fmaxf(d2, 0.f));
  }
  int start = argmax256(rsum, sv, si);
  if (t == 0) fpsIdx[0] = start;
  float dot0 = x * px[start] + y * py[start] + z * pz[start];
  float mind = sqrtf(fmaxf(n + pn[start] - 2.f * dot0, 0.f));
  for (int it = 1; it < KCL; ++it) {
    int far = argmax256(mind, sv, si);
    if (t == 0) fpsIdx[it] = far;
    float dot = x * px[far] + y * py[far] + z * pz[far];
    mind = fminf(mind, sqrtf(fmaxf(n + pn[far] - 2.f * dot, 0.f)));
  }
  __syncthreads();
  if (t < KCL) {
    int p = fpsIdx[t];
    centers0[t * 3 + 0] = px[p];
    centers0[t * 3 + 1] = py[p];
    centers0[t * 3 + 2] = pz[p];
  }
}

// ---------------- K2: MFMA Gram, 128x128 upper-tri tiles, 3 chains ---------------
// grid (3 pairs, 8 batches, 16 splits) = 384 blocks x 512 threads (8 waves)
__global__ __launch_bounds__(512, 2) void k_gemm_mfma(const float* __restrict__ ff,
                                                      float* __restrict__ Pp) {
  __shared__ _Float16 Ah[128][40];   // pad 32->40: frag reads 2-way bank alias (free)
  __shared__ _Float16 Al[128][40];
  __shared__ _Float16 Bh[128][40];
  __shared__ _Float16 Bl[128][40];

  const int tid = threadIdx.x;
  const int ti = TItab[blockIdx.x], tj = TJtab[blockIdx.x];
  const bool diag = (ti == tj);
  const int b = blockIdx.y, sp = blockIdx.z;
  const int wave = tid >> 6, lane = tid & 63;
  const int wr = wave >> 1, wc = wave & 1;        // wave: 32 rows x 64 cols
  const int lrow = lane & 15, q = lane >> 4;

  const int sr = tid >> 2;            // 0..127
  const int sc = (tid & 3) * 8;       // 0,8,16,24
  const float* gA = ff + ((size_t)(b * NC + ti * 128 + sr)) * DF + sp * KC + sc;
  const float* gB = ff + ((size_t)(b * NC + tj * 128 + sr)) * DF + sp * KC + sc;

  floatx4 a1[2][4], a2[2][4], a3[2][4];
  #pragma unroll
  for (int i = 0; i < 2; ++i)
    #pragma unroll
    for (int j = 0; j < 4; ++j) { a1[i][j] = (floatx4)0.f; a2[i][j] = (floatx4)0.f; a3[i][j] = (floatx4)0.f; }

  float4 ra0 = *(const float4*)(gA), ra1 = *(const float4*)(gA + 4);
  float4 rb0 = make_float4(0.f, 0.f, 0.f, 0.f), rb1 = rb0;
  if (!diag) { rb0 = *(const float4*)(gB); rb1 = *(const float4*)(gB + 4); }
  gA += BK; gB += BK;

  for (int it = 0; it < ITERS; ++it) {
    float fa[8] = {ra0.x, ra0.y, ra0.z, ra0.w, ra1.x, ra1.y, ra1.z, ra1.w};
    half8 ah, al;
    #pragma unroll
    for (int e = 0; e < 8; ++e) {
      _Float16 h = (_Float16)fa[e];
      ah[e] = h;
      al[e] = (_Float16)(fa[e] - (float)h);
    }
    half8 bh, bl;
    if (!diag) {
      float fb[8] = {rb0.x, rb0.y, rb0.z, rb0.w, rb1.x, rb1.y, rb1.z, rb1.w};
      #pragma unroll
      for (int e = 0; e < 8; ++e) {
        _Float16 h = (_Float16)fb[e];
        bh[e] = h;
        bl[e] = (_Float16)(fb[e] - (float)h);
      }
    }
    __syncthreads();
    *(half8*)&Ah[sr][sc] = ah;
    *(half8*)&Al[sr][sc] = al;
    if (!diag) {
      *(half8*)&Bh[sr][sc] = bh;
      *(half8*)&Bl[sr][sc] = bl;
    }
    __syncthreads();
    if (it + 1 < ITERS) {
      ra0 = *(const float4*)(gA); ra1 = *(const float4*)(gA + 4);
      if (!diag) { rb0 = *(const float4*)(gB); rb1 = *(const float4*)(gB + 4); }
      gA += BK; gB += BK;
    }
    const _Float16* bhp = diag ? &Ah[0][0] : &Bh[0][0];
    const _Float16* blp = diag ? &Al[0][0] : &Bl[0][0];
    half8 af[2], lf[2];
    #pragma unroll
    for (int i = 0; i < 2; ++i) {
      af[i] = *(const half8*)&Ah[wr * 32 + i * 16 + lrow][q * 8];
      lf[i] = *(const half8*)&Al[wr * 32 + i * 16 + lrow][q * 8];
    }
    #pragma unroll
    for (int j = 0; j < 4; ++j) {
      half8 bhf = *(const half8*)(bhp + (wc * 64 + j * 16 + lrow) * 40 + q * 8);
      half8 blf = *(const half8*)(blp + (wc * 64 + j * 16 + lrow) * 40 + q * 8);
      #pragma unroll
      for (int i = 0; i < 2; ++i) {
        a1[i][j] = __builtin_amdgcn_mfma_f32_16x16x32_f16(af[i], bhf, a1[i][j], 0, 0, 0);
        a2[i][j] = __builtin_amdgcn_mfma_f32_16x16x32_f16(af[i], blf, a2[i][j], 0, 0, 0);
        a3[i][j] = __builtin_amdgcn_mfma_f32_16x16x32_f16(lf[i], bhf, a3[i][j], 0, 0, 0);
      }
    }
  }

  float* Pb = Pp + (size_t)(sp * NB + b) * NC * NC;
  #pragma unroll
  for (int i = 0; i < 2; ++i) {
    int grow = ti * 128 + wr * 32 + i * 16 + q * 4;
    #pragma unroll
    for (int j = 0; j < 4; ++j) {
      int gcol = tj * 128 + wc * 64 + j * 16 + lrow;
      float4 v;
      v.x = a1[i][j][0] + a2[i][j][0] + a3[i][j][0];
      v.y = a1[i][j][1] + a2[i][j][1] + a3[i][j][1];
      v.z = a1[i][j][2] + a2[i][j][2] + a3[i][j][2];
      v.w = a1[i][j][3] + a2[i][j][3] + a3[i][j][3];
      Pb[(size_t)(grow + 0) * NC + gcol] = v.x;
      Pb[(size_t)(grow + 1) * NC + gcol] = v.y;
      Pb[(size_t)(grow + 2) * NC + gcol] = v.z;
      Pb[(size_t)(grow + 3) * NC + gcol] = v.w;
      if (!diag) *(float4*)&Pb[(size_t)gcol * NC + grow] = v;  // mirror (lower block)
    }
  }
}

// ---------------- K3: diag + formD + column partial sums (fused) -----------------
// grid 256 blocks: b = g>>5, 8 rows each. rs[b][t] += column partials (atomic).
__global__ __launch_bounds__(256) void k_formD(const float* __restrict__ Pp,
                                               float* __restrict__ Db,
                                               float* __restrict__ rs) {
  __shared__ float dg_s[NC];
  const int t = threadIdx.x;
  const int b = blockIdx.x >> 5, i0 = (blockIdx.x & 31) * 8;
  float s = 0.f;
  #pragma unroll
  for (int sp = 0; sp < SPLITS; ++sp)
    s += Pp[((size_t)(sp * NB + b) * NC + t) * NC + t];
  dg_s[t] = s;
  __syncthreads();
  float colsum = 0.f;
  for (int ii = 0; ii < 8; ++ii) {
    int i = i0 + ii;
    float acc = 0.f;
    #pragma unroll
    for (int sp = 0; sp < SPLITS; ++sp)
      acc += Pp[((size_t)(sp * NB + b) * NC + i) * NC + t];
    float d2 = dg_s[i] + dg_s[t] - 2.f * acc;
    float d = sqrtf(fmaxf(d2, 0.f));
    Db[((size_t)b * NC + i) * NC + t] = d;
    colsum += d;
  }
  atomicAdd(&rs[b * NC + t], colsum);
}

// ---------------- K4: per-batch FPS on Db (8 blocks), rs precomputed -------------
__global__ __launch_bounds__(256) void k_fps_b(const float* __restrict__ Db,
                                               const float* __restrict__ rs,
                                               const float* __restrict__ pe,
                                               float* __restrict__ ccoord) {
  int b = blockIdx.x, t = threadIdx.x;
  const float* D = Db + (size_t)b * NC * NC;
  __shared__ float sv[NC]; __shared__ int si[NC];
  __shared__ int fpsIdx[KCL];
  int start = argmax256(rs[b * NC + t], sv, si);
  if (t == 0) fpsIdx[0] = start;
  float mind = D[start * NC + t];   // symmetric row==col
  for (int it = 1; it < KCL; ++it) {
    int far = argmax256(mind, sv, si);
    if (t == 0) fpsIdx[it] = far;
    mind = fminf(mind, D[far * NC + t]);
  }
  __syncthreads();
  if (t < KCL) {
    int p = fpsIdx[t];
    ccoord[(b * KCL + t) * 3 + 0] = pe[(b * NC + p) * 3 + 0];
    ccoord[(b * KCL + t) * 3 + 1] = pe[(b * NC + p) * 3 + 1];
    ccoord[(b * KCL + t) * 3 + 2] = pe[(b * NC + p) * 3 + 2];
  }
}

// ---------------- K5: temp_assign + seg-means + matching + update + capacity -----
__global__ __launch_bounds__(256) void k_final(const float* __restrict__ pe,
                                               const float* __restrict__ ccoord,
                                               const float* __restrict__ centers0,
                                               int* __restrict__ outp) {
  __shared__ float cc[NB * KCL * 3];
  __shared__ float cn[NB * KCL];
  __shared__ float sums[KCL][3];
  __shared__ int cnts[KCL];
  __shared__ float avg[KCL][3];
  __shared__ float an[KCL];
  __shared__ float c0[KCL * 3];
  __shared__ float c1x[KCL], c1y[KCL], c1z[KCL], c1n[KCL];
  __shared__ int order[NC][KCL];
  int t = threadIdx.x;
  for (int i = t; i < NB * KCL * 3; i += 256) cc[i] = ccoord[i];
  if (t < KCL * 3) c0[t] = centers0[t];
  if (t < KCL) { sums[t][0] = 0.f; sums[t][1] = 0.f; sums[t][2] = 0.f; cnts[t] = 0; }
  __syncthreads();
  if (t < NB * KCL) {
    float x = cc[t * 3], y = cc[t * 3 + 1], z = cc[t * 3 + 2];
    cn[t] = x * x + y * y + z * z;
  }
  __syncthreads();
  for (int b = 0; b < NB; ++b) {
    int p = b * NC + t;
    float x = pe[p * 3], y = pe[p * 3 + 1], z = pe[p * 3 + 2];
    float n = x * x + y * y + z * z;
    float best = 3.4e38f; int bi = 0;
    #pragma unroll
    for (int k = 0; k < KCL; ++k) {
      int c = b * KCL + k;
      float dot = x * cc[c * 3] + y * cc[c * 3 + 1] + z * cc[c * 3 + 2];
      float d2 = fmaxf(n + cn[c] - 2.f * dot, 0.f);
      if (d2 < best) { best = d2; bi = k; }
    }
    atomicAdd(&sums[bi][0], x);
    atomicAdd(&sums[bi][1], y);
    atomicAdd(&sums[bi][2], z);
    atomicAdd(&cnts[bi], 1);
  }
  __syncthreads();
  if (t < KCL) {
    float c = (float)cnts[t];
    float inv = 1.f / fmaxf(c, 1.f);
    float ax = (cnts[t] > 0) ? sums[t][0] * inv : 0.f;
    float ay = (cnts[t] > 0) ? sums[t][1] * inv : 0.f;
    float az = (cnts[t] > 0) ? sums[t][2] * inv : 0.f;
    avg[t][0] = ax; avg[t][1] = ay; avg[t][2] = az;
    an[t] = ax * ax + ay * ay + az * az;
  }
  __syncthreads();
  if (t < KCL) {
    float x = c0[t * 3], y = c0[t * 3 + 1], z = c0[t * 3 + 2];
    float n = x * x + y * y + z * z;
    float best = 3.4e38f; int bi = 0;
    #pragma unroll
    for (int j = 0; j < KCL; ++j) {
      float dot = x * avg[j][0] + y * avg[j][1] + z * avg[j][2];
      float d2 = fmaxf(n + an[j] - 2.f * dot, 0.f);
      if (d2 < best) { best = d2; bi = j; }
    }
    float nx = 0.8f * x + 0.2f * avg[bi][0];
    float ny = 0.8f * y + 0.2f * avg[bi][1];
    float nz = 0.8f * z + 0.2f * avg[bi][2];
    c1x[t] = nx; c1y[t] = ny; c1z[t] = nz;
    c1n[t] = nx * nx + ny * ny + nz * nz;
  }
  __syncthreads();
  {
    float x = pe[t * 3], y = pe[t * 3 + 1], z = pe[t * 3 + 2];
    float n = x * x + y * y + z * z;
    float v[KCL];
    #pragma unroll
    for (int k = 0; k < KCL; ++k) {
      float dot = x * c1x[k] + y * c1y[k] + z * c1z[k];
      v[k] = fmaxf(n + c1n[k] - 2.f * dot, 0.f);
    }
    bool used[KCL];
    #pragma unroll
    for (int k = 0; k < KCL; ++k) used[k] = false;
    for (int r = 0; r < KCL; ++r) {
      float best = 3.4e38f; int bi = 0;
      #pragma unroll
      for (int j = 0; j < KCL; ++j) {
        if (!used[j] && v[j] < best) { best = v[j]; bi = j; }
      }
      order[t][r] = bi;
      used[bi] = true;
    }
  }
  __syncthreads();
  if (t < 64) {
    int cnt = 0;
    int cur = (t < KCL) ? order[0][t] : 0;
    for (int i = 0; i < NC; ++i) {
      int nxt = (t < KCL && i + 1 < NC) ? order[i + 1][t] : 0;
      int ccur = __shfl(cnt, cur);
      bool avail = (t < KCL) && (ccur < 16);
      unsigned long long m = __ballot(avail);
      int chosen;
      if (m != 0ull) {
        int rank = __ffsll((unsigned long long)m) - 1;
        chosen = __shfl(cur, rank);
      } else {
        chosen = __shfl(cur, 0);
      }
      if (t == chosen) cnt++;
      if (t == 0) outp[i] = chosen;
      cur = nxt;
    }
  }
}

extern "C" void kernel_launch(void* const* d_in, const int* in_sizes, int n_in,
                              void* d_out, int out_size, void* d_ws, size_t ws_size,
                              hipStream_t stream) {
  (void)in_sizes; (void)n_in; (void)out_size; (void)ws_size;
  const float* features = (const float*)d_in[0];
  const float* pe = (const float*)d_in[1];
  char* ws = (char*)d_ws;
  float* Pp       = (float*)(ws);                  // 16*8*256*256*4 = 32 MiB
  float* Db       = (float*)(ws + 33554432);       // 2 MiB
  float* rs       = (float*)(ws + 35651584);       // 8 KiB
  float* centers0 = (float*)(ws + 35659776);       // 192 B
  float* ccoord   = (float*)(ws + 35660288);       // 1.5 KiB
  int*   outp     = (int*)d_out;

  hipLaunchKernelGGL(k_pre, dim3(1), dim3(256), 0, stream, pe, centers0, rs);
  hipLaunchKernelGGL(k_gemm_mfma, dim3(NTILE, NB, SPLITS), dim3(512), 0, stream, features, Pp);
  hipLaunchKernelGGL(k_formD, dim3(256), dim3(256), 0, stream, Pp, Db, rs);
  hipLaunchKernelGGL(k_fps_b, dim3(NB), dim3(256), 0, stream, Db, rs, pe, ccoord);
  hipLaunchKernelGGL(k_final, dim3(1), dim3(256), 0, stream, pe, ccoord, centers0, outp);
}

// Round 6
// 335.800 us; speedup vs baseline: 1.5617x; 1.0911x over previous
//
#include <hip/hip_runtime.h>

#define NB 8
#define NC 256
#define DF 16384
#define KCL 16
#define SPLITS 16
#define KC (DF / SPLITS)     // 1024
#define BK 32
#define ITERS (KC / BK)      // 32
#define NPAIR 3              // 128x128 upper-tri pairs: (0,0),(0,1),(1,1)
#define GEMM_BLOCKS (NPAIR * 2 * NB * SPLITS)   // 6*8*16 = 768

typedef _Float16 half8 __attribute__((ext_vector_type(8)));
typedef _Float16 half4_t __attribute__((ext_vector_type(4)));
typedef float floatx4 __attribute__((ext_vector_type(4)));

__device__ const int TItab[NPAIR] = {0,0,1};
__device__ const int TJtab[NPAIR] = {0,1,1};

// ---------------- argmax over 256 threads (first occurrence) ---------------------
__device__ __forceinline__ int argmax256(float v, float* sv, int* si) {
  int t = threadIdx.x;
  sv[t] = v; si[t] = t;
  __syncthreads();
  #pragma unroll
  for (int s = 128; s >= 1; s >>= 1) {
    if (t < s) {
      float a = sv[t], b = sv[t + s];
      int ia = si[t], ib = si[t + s];
      if (b > a || (b == a && ib < ia)) { sv[t] = b; si[t] = ib; }
    }
    __syncthreads();
  }
  int r = si[0];
  __syncthreads();
  return r;
}

// ---------------- argmax over 512 threads via pointers (first occurrence) --------
__device__ __forceinline__ int argmax512p(float v, float* sv, int* si) {
  int t = threadIdx.x;
  sv[t] = v; si[t] = t;
  __syncthreads();
  #pragma unroll
  for (int s = 256; s >= 1; s >>= 1) {
    if (t < s) {
      float a = sv[t], b = sv[t + s];
      int ia = si[t], ib = si[t + s];
      if (b > a || (b == a && ib < ia)) { sv[t] = b; si[t] = ib; }
    }
    __syncthreads();
  }
  int r = si[0];
  __syncthreads();
  return r;
}

// ---------------- K1: fused [gemm 768 blocks | pos-FPS block 768] ----------------
// gemm: 128x64 col-half tiles of the upper-tri pairs, 3 f16 chains (hi/lo split)
__global__ __launch_bounds__(512, 3) void k_gemm_pre(const float* __restrict__ ff,
                                                     const float* __restrict__ pe,
                                                     float* __restrict__ Pp,
                                                     float* __restrict__ centers0,
                                                     float* __restrict__ rs) {
  __shared__ _Float16 Ah[128][40];   // pad 32->40: frag reads 2-way bank alias (free)
  __shared__ _Float16 Al[128][40];
  __shared__ _Float16 Bh[64][40];
  __shared__ _Float16 Bl[64][40];

  const int bid = blockIdx.x;
  const int tid = threadIdx.x;

  if (bid == GEMM_BLOCKS) {
    // ---- pos-FPS (512 threads; arrays aliased onto gemm LDS) ----
    float* sm = (float*)&Ah[0][0];
    float* px = sm;        float* py = sm + 256;
    float* pz = sm + 512;  float* pn = sm + 768;
    float* sv = sm + 1024; int*   si = (int*)(sm + 1536);
    int* fpsIdx = (int*)(sm + 2048);
    const int t = tid;
    for (int i = t; i < NB * NC; i += 512) rs[i] = 0.f;   // zero rs (ws poisoned)
    const bool valid = t < NC;
    float x = 0.f, y = 0.f, z = 0.f, n = 0.f;
    if (valid) {
      x = pe[t * 3 + 0]; y = pe[t * 3 + 1]; z = pe[t * 3 + 2];
      n = x * x + y * y + z * z;
      px[t] = x; py[t] = y; pz[t] = z; pn[t] = n;
    }
    __syncthreads();
    float rsum = -3.4e38f;
    if (valid) {
      rsum = 0.f;
      for (int j = 0; j < NC; ++j) {
        float dot = x * px[j] + y * py[j] + z * pz[j];
        rsum += sqrtf(fmaxf(n + pn[j] - 2.f * dot, 0.f));
      }
    }
    int start = argmax512p(rsum, sv, si);
    if (t == 0) fpsIdx[0] = start;
    float mind = -3.4e38f;
    if (valid) {
      float dot0 = x * px[start] + y * py[start] + z * pz[start];
      mind = sqrtf(fmaxf(n + pn[start] - 2.f * dot0, 0.f));
    }
    for (int it = 1; it < KCL; ++it) {
      int far = argmax512p(mind, sv, si);
      if (t == 0) fpsIdx[it] = far;
      if (valid) {
        float dot = x * px[far] + y * py[far] + z * pz[far];
        mind = fminf(mind, sqrtf(fmaxf(n + pn[far] - 2.f * dot, 0.f)));
      }
    }
    __syncthreads();
    if (t < KCL) {
      int p = fpsIdx[t];
      centers0[t * 3 + 0] = px[p];
      centers0[t * 3 + 1] = py[p];
      centers0[t * 3 + 2] = pz[p];
    }
    return;
  }

  // ---- gemm block ----
  const int tc = bid % 6;
  const int b  = (bid / 6) & 7;
  const int sp = bid / 48;
  const int pair = tc >> 1, ch = tc & 1;
  const int ti = TItab[pair], tj = TJtab[pair];
  const bool diag = (ti == tj);

  const int wave = tid >> 6, lane = tid & 63;
  const int wr = wave >> 1, wc = wave & 1;    // 8 waves: 4 row-strips x 2 col-strips
  const int lrow = lane & 15, q = lane >> 4;

  // A staging: 128 rows x 32 cols, 8 floats/thread
  const int srA = tid >> 2, scA = (tid & 3) * 8;
  // B staging: 64 rows x 32 cols, 4 floats/thread
  const int srB = tid >> 3, scB = (tid & 7) * 4;
  const float* gA = ff + ((size_t)(b * NC + ti * 128 + srA)) * DF + sp * KC + scA;
  const float* gB = ff + ((size_t)(b * NC + tj * 128 + ch * 64 + srB)) * DF + sp * KC + scB;

  floatx4 a1[2][2], a2[2][2], a3[2][2];
  #pragma unroll
  for (int i = 0; i < 2; ++i)
    #pragma unroll
    for (int j = 0; j < 2; ++j) { a1[i][j] = (floatx4)0.f; a2[i][j] = (floatx4)0.f; a3[i][j] = (floatx4)0.f; }

  float4 ra0 = *(const float4*)(gA), ra1 = *(const float4*)(gA + 4);
  float4 rb = make_float4(0.f, 0.f, 0.f, 0.f);
  if (!diag) rb = *(const float4*)(gB);
  gA += BK; gB += BK;

  for (int it = 0; it < ITERS; ++it) {
    float fa[8] = {ra0.x, ra0.y, ra0.z, ra0.w, ra1.x, ra1.y, ra1.z, ra1.w};
    half8 ah, al;
    #pragma unroll
    for (int e = 0; e < 8; ++e) {
      _Float16 h = (_Float16)fa[e];
      ah[e] = h;
      al[e] = (_Float16)(fa[e] - (float)h);
    }
    half4_t bh4, bl4;
    if (!diag) {
      float fb[4] = {rb.x, rb.y, rb.z, rb.w};
      #pragma unroll
      for (int e = 0; e < 4; ++e) {
        _Float16 h = (_Float16)fb[e];
        bh4[e] = h;
        bl4[e] = (_Float16)(fb[e] - (float)h);
      }
    }
    __syncthreads();   // previous iter's frag reads complete
    *(half8*)&Ah[srA][scA] = ah;
    *(half8*)&Al[srA][scA] = al;
    if (!diag) {
      *(half4_t*)&Bh[srB][scB] = bh4;
      *(half4_t*)&Bl[srB][scB] = bl4;
    }
    __syncthreads();   // tiles visible
    if (it + 1 < ITERS) {
      ra0 = *(const float4*)(gA); ra1 = *(const float4*)(gA + 4);
      if (!diag) rb = *(const float4*)(gB);
      gA += BK; gB += BK;
    }
    // diag blocks read B-frags from the A tile at row offset ch*64 (same stride 40)
    const _Float16* bhp = diag ? &Ah[ch * 64][0] : &Bh[0][0];
    const _Float16* blp = diag ? &Al[ch * 64][0] : &Bl[0][0];
    half8 af[2], lf[2];
    #pragma unroll
    for (int i = 0; i < 2; ++i) {
      af[i] = *(const half8*)&Ah[wr * 32 + i * 16 + lrow][q * 8];
      lf[i] = *(const half8*)&Al[wr * 32 + i * 16 + lrow][q * 8];
    }
    #pragma unroll
    for (int j = 0; j < 2; ++j) {
      half8 bhf = *(const half8*)(bhp + (wc * 32 + j * 16 + lrow) * 40 + q * 8);
      half8 blf = *(const half8*)(blp + (wc * 32 + j * 16 + lrow) * 40 + q * 8);
      #pragma unroll
      for (int i = 0; i < 2; ++i) {
        a1[i][j] = __builtin_amdgcn_mfma_f32_16x16x32_f16(af[i], bhf, a1[i][j], 0, 0, 0);
        a2[i][j] = __builtin_amdgcn_mfma_f32_16x16x32_f16(af[i], blf, a2[i][j], 0, 0, 0);
        a3[i][j] = __builtin_amdgcn_mfma_f32_16x16x32_f16(lf[i], bhf, a3[i][j], 0, 0, 0);
      }
    }
  }

  // epilogue: S = a1+a2+a3. Diag 128x128 blocks fully covered by both halves -> no mirror.
  float* Pb = Pp + (size_t)(sp * NB + b) * NC * NC;
  #pragma unroll
  for (int i = 0; i < 2; ++i) {
    int grow = ti * 128 + wr * 32 + i * 16 + q * 4;
    #pragma unroll
    for (int j = 0; j < 2; ++j) {
      int gcol = tj * 128 + ch * 64 + wc * 32 + j * 16 + lrow;
      float4 v;
      v.x = a1[i][j][0] + a2[i][j][0] + a3[i][j][0];
      v.y = a1[i][j][1] + a2[i][j][1] + a3[i][j][1];
      v.z = a1[i][j][2] + a2[i][j][2] + a3[i][j][2];
      v.w = a1[i][j][3] + a2[i][j][3] + a3[i][j][3];
      Pb[(size_t)(grow + 0) * NC + gcol] = v.x;
      Pb[(size_t)(grow + 1) * NC + gcol] = v.y;
      Pb[(size_t)(grow + 2) * NC + gcol] = v.z;
      Pb[(size_t)(grow + 3) * NC + gcol] = v.w;
      if (!diag) *(float4*)&Pb[(size_t)gcol * NC + grow] = v;  // mirror (lower block)
    }
  }
}

// ---------------- K2: diag + formD + column partial sums (fused) -----------------
__global__ __launch_bounds__(256) void k_formD(const float* __restrict__ Pp,
                                               float* __restrict__ Db,
                                               float* __restrict__ rs) {
  __shared__ float dg_s[NC];
  const int t = threadIdx.x;
  const int b = blockIdx.x >> 5, i0 = (blockIdx.x & 31) * 8;
  float s = 0.f;
  #pragma unroll
  for (int sp = 0; sp < SPLITS; ++sp)
    s += Pp[((size_t)(sp * NB + b) * NC + t) * NC + t];
  dg_s[t] = s;
  __syncthreads();
  float colsum = 0.f;
  for (int ii = 0; ii < 8; ++ii) {
    int i = i0 + ii;
    float acc = 0.f;
    #pragma unroll
    for (int sp = 0; sp < SPLITS; ++sp)
      acc += Pp[((size_t)(sp * NB + b) * NC + i) * NC + t];
    float d2 = dg_s[i] + dg_s[t] - 2.f * acc;
    float d = sqrtf(fmaxf(d2, 0.f));
    Db[((size_t)b * NC + i) * NC + t] = d;
    colsum += d;
  }
  atomicAdd(&rs[b * NC + t], colsum);
}

// ---------------- K3: per-batch FPS on Db (8 blocks), rs precomputed -------------
__global__ __launch_bounds__(256) void k_fps_b(const float* __restrict__ Db,
                                               const float* __restrict__ rs,
                                               const float* __restrict__ pe,
                                               float* __restrict__ ccoord) {
  int b = blockIdx.x, t = threadIdx.x;
  const float* D = Db + (size_t)b * NC * NC;
  __shared__ float sv[NC]; __shared__ int si[NC];
  __shared__ int fpsIdx[KCL];
  int start = argmax256(rs[b * NC + t], sv, si);
  if (t == 0) fpsIdx[0] = start;
  float mind = D[start * NC + t];   // symmetric row==col
  for (int it = 1; it < KCL; ++it) {
    int far = argmax256(mind, sv, si);
    if (t == 0) fpsIdx[it] = far;
    mind = fminf(mind, D[far * NC + t]);
  }
  __syncthreads();
  if (t < KCL) {
    int p = fpsIdx[t];
    ccoord[(b * KCL + t) * 3 + 0] = pe[(b * NC + p) * 3 + 0];
    ccoord[(b * KCL + t) * 3 + 1] = pe[(b * NC + p) * 3 + 1];
    ccoord[(b * KCL + t) * 3 + 2] = pe[(b * NC + p) * 3 + 2];
  }
}

// ---------------- K4: temp_assign + seg-means + matching + update + capacity -----
__global__ __launch_bounds__(256) void k_final(const float* __restrict__ pe,
                                               const float* __restrict__ ccoord,
                                               const float* __restrict__ centers0,
                                               int* __restrict__ outp) {
  __shared__ float cc[NB * KCL * 3];
  __shared__ float cn[NB * KCL];
  __shared__ float sums[KCL][3];
  __shared__ int cnts[KCL];
  __shared__ float avg[KCL][3];
  __shared__ float an[KCL];
  __shared__ float c0[KCL * 3];
  __shared__ float c1x[KCL], c1y[KCL], c1z[KCL], c1n[KCL];
  __shared__ int order[NC][KCL];
  int t = threadIdx.x;
  for (int i = t; i < NB * KCL * 3; i += 256) cc[i] = ccoord[i];
  if (t < KCL * 3) c0[t] = centers0[t];
  if (t < KCL) { sums[t][0] = 0.f; sums[t][1] = 0.f; sums[t][2] = 0.f; cnts[t] = 0; }
  __syncthreads();
  if (t < NB * KCL) {
    float x = cc[t * 3], y = cc[t * 3 + 1], z = cc[t * 3 + 2];
    cn[t] = x * x + y * y + z * z;
  }
  __syncthreads();
  for (int b = 0; b < NB; ++b) {
    int p = b * NC + t;
    float x = pe[p * 3], y = pe[p * 3 + 1], z = pe[p * 3 + 2];
    float n = x * x + y * y + z * z;
    float best = 3.4e38f; int bi = 0;
    #pragma unroll
    for (int k = 0; k < KCL; ++k) {
      int c = b * KCL + k;
      float dot = x * cc[c * 3] + y * cc[c * 3 + 1] + z * cc[c * 3 + 2];
      float d2 = fmaxf(n + cn[c] - 2.f * dot, 0.f);
      if (d2 < best) { best = d2; bi = k; }
    }
    atomicAdd(&sums[bi][0], x);
    atomicAdd(&sums[bi][1], y);
    atomicAdd(&sums[bi][2], z);
    atomicAdd(&cnts[bi], 1);
  }
  __syncthreads();
  if (t < KCL) {
    float c = (float)cnts[t];
    float inv = 1.f / fmaxf(c, 1.f);
    float ax = (cnts[t] > 0) ? sums[t][0] * inv : 0.f;
    float ay = (cnts[t] > 0) ? sums[t][1] * inv : 0.f;
    float az = (cnts[t] > 0) ? sums[t][2] * inv : 0.f;
    avg[t][0] = ax; avg[t][1] = ay; avg[t][2] = az;
    an[t] = ax * ax + ay * ay + az * az;
  }
  __syncthreads();
  if (t < KCL) {
    float x = c0[t * 3], y = c0[t * 3 + 1], z = c0[t * 3 + 2];
    float n = x * x + y * y + z * z;
    float best = 3.4e38f; int bi = 0;
    #pragma unroll
    for (int j = 0; j < KCL; ++j) {
      float dot = x * avg[j][0] + y * avg[j][1] + z * avg[j][2];
      float d2 = fmaxf(n + an[j] - 2.f * dot, 0.f);
      if (d2 < best) { best = d2; bi = j; }
    }
    float nx = 0.8f * x + 0.2f * avg[bi][0];
    float ny = 0.8f * y + 0.2f * avg[bi][1];
    float nz = 0.8f * z + 0.2f * avg[bi][2];
    c1x[t] = nx; c1y[t] = ny; c1z[t] = nz;
    c1n[t] = nx * nx + ny * ny + nz * nz;
  }
  __syncthreads();
  {
    float x = pe[t * 3], y = pe[t * 3 + 1], z = pe[t * 3 + 2];
    float n = x * x + y * y + z * z;
    float v[KCL];
    #pragma unroll
    for (int k = 0; k < KCL; ++k) {
      float dot = x * c1x[k] + y * c1y[k] + z * c1z[k];
      v[k] = fmaxf(n + c1n[k] - 2.f * dot, 0.f);
    }
    bool used[KCL];
    #pragma unroll
    for (int k = 0; k < KCL; ++k) used[k] = false;
    for (int r = 0; r < KCL; ++r) {
      float best = 3.4e38f; int bi = 0;
      #pragma unroll
      for (int j = 0; j < KCL; ++j) {
        if (!used[j] && v[j] < best) { best = v[j]; bi = j; }
      }
      order[t][r] = bi;
      used[bi] = true;
    }
  }
  __syncthreads();
  if (t < 64) {
    int cnt = 0;
    int cur = (t < KCL) ? order[0][t] : 0;
    for (int i = 0; i < NC; ++i) {
      int nxt = (t < KCL && i + 1 < NC) ? order[i + 1][t] : 0;
      int ccur = __shfl(cnt, cur);
      bool avail = (t < KCL) && (ccur < 16);
      unsigned long long m = __ballot(avail);
      int chosen;
      if (m != 0ull) {
        int rank = __ffsll((unsigned long long)m) - 1;
        chosen = __shfl(cur, rank);
      } else {
        chosen = __shfl(cur, 0);
      }
      if (t == chosen) cnt++;
      if (t == 0) outp[i] = chosen;
      cur = nxt;
    }
  }
}

extern "C" void kernel_launch(void* const* d_in, const int* in_sizes, int n_in,
                              void* d_out, int out_size, void* d_ws, size_t ws_size,
                              hipStream_t stream) {
  (void)in_sizes; (void)n_in; (void)out_size; (void)ws_size;
  const float* features = (const float*)d_in[0];
  const float* pe = (const float*)d_in[1];
  char* ws = (char*)d_ws;
  float* Pp       = (float*)(ws);                  // 16*8*256*256*4 = 32 MiB
  float* Db       = (float*)(ws + 33554432);       // 2 MiB
  float* rs       = (float*)(ws + 35651584);       // 8 KiB
  float* centers0 = (float*)(ws + 35659776);       // 192 B
  float* ccoord   = (float*)(ws + 35660288);       // 1.5 KiB
  int*   outp     = (int*)d_out;

  hipLaunchKernelGGL(k_gemm_pre, dim3(GEMM_BLOCKS + 1), dim3(512), 0, stream,
                     features, pe, Pp, centers0, rs);
  hipLaunchKernelGGL(k_formD, dim3(256), dim3(256), 0, stream, Pp, Db, rs);
  hipLaunchKernelGGL(k_fps_b, dim3(NB), dim3(256), 0, stream, Db, rs, pe, ccoord);
  hipLaunchKernelGGL(k_final, dim3(1), dim3(256), 0, stream, pe, ccoord, centers0, outp);
}